// Round 2
// baseline (725.692 us; speedup 1.0000x reference)
//
#include <hip/hip_runtime.h>
#include <hip/hip_bf16.h>

#define H_DIM 2048
#define M_DIM 1408
#define N_TOK 1024
#define N_EXP 8   // routed experts; expert index 8 = shared expert

typedef __attribute__((ext_vector_type(8))) short bf16x8;
typedef __attribute__((ext_vector_type(4))) float f32x4;

__device__ __forceinline__ unsigned short f2bf(float f) {
  __hip_bfloat16 h = __float2bfloat16(f);
  return __builtin_bit_cast(unsigned short, h);
}

__device__ __forceinline__ uint4 cvt8(const float4 f0, const float4 f1) {
  uint4 o;
  o.x = (unsigned)f2bf(f0.x) | ((unsigned)f2bf(f0.y) << 16);
  o.y = (unsigned)f2bf(f0.z) | ((unsigned)f2bf(f0.w) << 16);
  o.z = (unsigned)f2bf(f1.x) | ((unsigned)f2bf(f1.y) << 16);
  o.w = (unsigned)f2bf(f1.z) | ((unsigned)f2bf(f1.w) << 16);
  return o;
}

// ---------------- K0: zero y + counters ----------------
__global__ void k_zero(float* __restrict__ y, int n4, int* __restrict__ cnt,
                       float* __restrict__ pi_sum) {
  int i = blockIdx.x * blockDim.x + threadIdx.x;
  if (i < n4) {
    float4 z = {0.f, 0.f, 0.f, 0.f};
    *(float4*)(y + (size_t)i * 4) = z;
  }
  if (blockIdx.x == 0 && threadIdx.x < 8) {
    cnt[threadIdx.x] = 0;
    pi_sum[threadIdx.x] = 0.f;
  }
}

// ---------------- K1: gate (fp32) + routing lists + x->bf16 ----------------
__global__ __launch_bounds__(256) void k_gate(
    const float* __restrict__ x, const float* __restrict__ gw,
    unsigned short* __restrict__ xb, int* __restrict__ cnt,
    float* __restrict__ pi_sum, int* __restrict__ tok_list,
    float* __restrict__ wgt_list) {
  const int lane = threadIdx.x & 63;
  const int wv = threadIdx.x >> 6;
  const int n = blockIdx.x * 4 + wv;
  const float* xr = x + (size_t)n * H_DIM;

  float acc[8] = {0.f, 0.f, 0.f, 0.f, 0.f, 0.f, 0.f, 0.f};
  for (int i = 0; i < H_DIM / 64; ++i) {
    float xv = xr[i * 64 + lane];
#pragma unroll
    for (int e = 0; e < 8; ++e) acc[e] += xv * gw[e * H_DIM + i * 64 + lane];
  }
#pragma unroll
  for (int e = 0; e < 8; ++e) {
    acc[e] += __shfl_xor(acc[e], 32, 64);
    acc[e] += __shfl_xor(acc[e], 16, 64);
    acc[e] += __shfl_xor(acc[e], 8, 64);
    acc[e] += __shfl_xor(acc[e], 4, 64);
    acc[e] += __shfl_xor(acc[e], 2, 64);
    acc[e] += __shfl_xor(acc[e], 1, 64);
  }

  // x -> bf16 (coalesced float4 loads, ushort4 stores)
  for (int j = 0; j < H_DIM / 256; ++j) {
    int idx = (j * 64 + lane) * 4;
    float4 v = *(const float4*)(xr + idx);
    ushort4 o;
    o.x = f2bf(v.x); o.y = f2bf(v.y); o.z = f2bf(v.z); o.w = f2bf(v.w);
    *(ushort4*)(xb + (size_t)n * H_DIM + idx) = o;
  }

  if (lane == 0) {
    float mx = acc[0];
#pragma unroll
    for (int e = 1; e < 8; ++e) mx = fmaxf(mx, acc[e]);
    float s[8], ssum = 0.f;
#pragma unroll
    for (int e = 0; e < 8; ++e) { s[e] = expf(acc[e] - mx); ssum += s[e]; }
    float inv = 1.f / ssum;
#pragma unroll
    for (int e = 0; e < 8; ++e) s[e] *= inv;  // softmax scores

    // top-2, earliest index wins ties (matches jax.lax.top_k)
    int i0 = 0;
#pragma unroll
    for (int e = 1; e < 8; ++e) if (s[e] > s[i0]) i0 = e;
    int i1 = (i0 == 0) ? 1 : 0;
#pragma unroll
    for (int e = 0; e < 8; ++e) if (e != i0 && s[e] > s[i1]) i1 = e;

    float w0 = s[i0], w1 = s[i1];
    float rs = 1.f / (w0 + w1 + 1e-20f);

#pragma unroll
    for (int e = 0; e < 8; ++e) atomicAdd(&pi_sum[e], s[e]);

    int p0 = atomicAdd(&cnt[i0], 1);
    tok_list[i0 * N_TOK + p0] = n;
    wgt_list[i0 * N_TOK + p0] = w0 * rs;
    int p1 = atomicAdd(&cnt[i1], 1);
    tok_list[i1 * N_TOK + p1] = n;
    wgt_list[i1 * N_TOK + p1] = w1 * rs;
  }
}

// ---------------- K2: gathered SwiGLU (gate&up fused) ----------------
// grid (M_DIM/64, 9, 4); block 256. Expert 8 = shared.
__global__ __launch_bounds__(256) void k_gemm1(
    const float* __restrict__ w_gate, const float* __restrict__ w_up,
    const float* __restrict__ sh_gate, const float* __restrict__ sh_up,
    const unsigned short* __restrict__ xb, const int* __restrict__ cnt,
    const int* __restrict__ tok_list, unsigned short* __restrict__ a_buf) {
  const int e = blockIdx.y;
  const int m0 = blockIdx.x * 64;
  const int cntE = (e == 8) ? N_TOK : cnt[e];
  const int t0 = blockIdx.z * 256;
  if (t0 >= cntE) return;
  const float* wg = (e == 8) ? sh_gate : w_gate + (size_t)e * (M_DIM * H_DIM);
  const float* wu = (e == 8) ? sh_up : w_up + (size_t)e * (M_DIM * H_DIM);

  __shared__ unsigned short Xs[64 * 64];
  __shared__ unsigned short Gs[64 * 64];
  __shared__ unsigned short Us[64 * 64];

  const int t = threadIdx.x;
  const int lane = t & 63;
  const int wm = (t >> 7) & 1;
  const int wn = (t >> 6) & 1;
  const int ra = t >> 3;        // 0..31
  const int rb = ra + 32;
  const int sl = t & 7;
  const int dxa = ra * 64 + ((sl ^ (ra & 7)) << 3);
  const int dxb = rb * 64 + ((sl ^ (rb & 7)) << 3);

  const float* wga = wg + (size_t)(m0 + ra) * H_DIM + sl * 8;
  const float* wgb = wg + (size_t)(m0 + rb) * H_DIM + sl * 8;
  const float* wua = wu + (size_t)(m0 + ra) * H_DIM + sl * 8;
  const float* wub = wu + (size_t)(m0 + rb) * H_DIM + sl * 8;

  for (int tt = 0; tt < 4; ++tt) {
    const int tb = t0 + tt * 64;
    if (tb >= cntE) break;
    const int rga = tb + ra, rgb = tb + rb;
    const int na = (e == 8) ? rga : (rga < cntE ? tok_list[e * N_TOK + rga] : 0);
    const int nb = (e == 8) ? rgb : (rgb < cntE ? tok_list[e * N_TOK + rgb] : 0);
    const unsigned short* xpa = xb + (size_t)na * H_DIM + sl * 8;
    const unsigned short* xpb = xb + (size_t)nb * H_DIM + sl * 8;

    f32x4 ag[2][2] = {};
    f32x4 au[2][2] = {};

    for (int kk = 0; kk < H_DIM / 64; ++kk) {
      *(uint4*)&Xs[dxa] = *(const uint4*)(xpa + kk * 64);
      *(uint4*)&Xs[dxb] = *(const uint4*)(xpb + kk * 64);
      {
        float4 f0 = *(const float4*)(wga + kk * 64);
        float4 f1 = *(const float4*)(wga + kk * 64 + 4);
        *(uint4*)&Gs[dxa] = cvt8(f0, f1);
        f0 = *(const float4*)(wgb + kk * 64);
        f1 = *(const float4*)(wgb + kk * 64 + 4);
        *(uint4*)&Gs[dxb] = cvt8(f0, f1);
        f0 = *(const float4*)(wua + kk * 64);
        f1 = *(const float4*)(wua + kk * 64 + 4);
        *(uint4*)&Us[dxa] = cvt8(f0, f1);
        f0 = *(const float4*)(wub + kk * 64);
        f1 = *(const float4*)(wub + kk * 64 + 4);
        *(uint4*)&Us[dxb] = cvt8(f0, f1);
      }
      __syncthreads();
#pragma unroll
      for (int ks = 0; ks < 2; ++ks) {
        const int sA = ks * 4 + (lane >> 4);
        bf16x8 a[2], bg[2], bu[2];
#pragma unroll
        for (int f = 0; f < 2; ++f) {
          const int r16 = wm * 32 + f * 16 + (lane & 15);
          a[f] = *(const bf16x8*)&Xs[r16 * 64 + ((sA ^ (r16 & 7)) << 3)];
          const int c16 = wn * 32 + f * 16 + (lane & 15);
          bg[f] = *(const bf16x8*)&Gs[c16 * 64 + ((sA ^ (c16 & 7)) << 3)];
          bu[f] = *(const bf16x8*)&Us[c16 * 64 + ((sA ^ (c16 & 7)) << 3)];
        }
#pragma unroll
        for (int fm = 0; fm < 2; ++fm)
#pragma unroll
          for (int fn = 0; fn < 2; ++fn) {
            ag[fm][fn] = __builtin_amdgcn_mfma_f32_16x16x32_bf16(a[fm], bg[fn], ag[fm][fn], 0, 0, 0);
            au[fm][fn] = __builtin_amdgcn_mfma_f32_16x16x32_bf16(a[fm], bu[fn], au[fm][fn], 0, 0, 0);
          }
      }
      __syncthreads();
    }
    // epilogue: silu(g)*u -> bf16 a_buf
#pragma unroll
    for (int fm = 0; fm < 2; ++fm)
#pragma unroll
      for (int fn = 0; fn < 2; ++fn)
#pragma unroll
        for (int rg = 0; rg < 4; ++rg) {
          const int row = tb + wm * 32 + fm * 16 + ((lane >> 4) << 2) + rg;
          const int col = m0 + wn * 32 + fn * 16 + (lane & 15);
          float g = ag[fm][fn][rg];
          float u = au[fm][fn][rg];
          float av = (g / (1.f + __expf(-g))) * u;
          a_buf[(size_t)(e * N_TOK + row) * M_DIM + col] = f2bf(av);
        }
  }
}

// ---------------- K3: down-proj + weighted scatter ----------------
// grid (H_DIM/64, 9, 4); block 256.
__global__ __launch_bounds__(256) void k_gemm2(
    const float* __restrict__ w_down, const float* __restrict__ sh_down,
    const unsigned short* __restrict__ a_buf, const int* __restrict__ cnt,
    const int* __restrict__ tok_list, const float* __restrict__ wgt_list,
    float* __restrict__ y) {
  const int e = blockIdx.y;
  const int h0 = blockIdx.x * 64;
  const int cntE = (e == 8) ? N_TOK : cnt[e];
  const int t0 = blockIdx.z * 256;
  if (t0 >= cntE) return;
  const float* wd = (e == 8) ? sh_down : w_down + (size_t)e * (H_DIM * M_DIM);

  __shared__ unsigned short As[64 * 64];
  __shared__ unsigned short Ws[64 * 64];

  const int t = threadIdx.x;
  const int lane = t & 63;
  const int wm = (t >> 7) & 1;
  const int wn = (t >> 6) & 1;
  const int ra = t >> 3, rb = ra + 32, sl = t & 7;
  const int dxa = ra * 64 + ((sl ^ (ra & 7)) << 3);
  const int dxb = rb * 64 + ((sl ^ (rb & 7)) << 3);

  const float* wda = wd + (size_t)(h0 + ra) * M_DIM + sl * 8;
  const float* wdb = wd + (size_t)(h0 + rb) * M_DIM + sl * 8;

  for (int tt = 0; tt < 4; ++tt) {
    const int tb = t0 + tt * 64;
    if (tb >= cntE) break;
    const unsigned short* apa = a_buf + (size_t)(e * N_TOK + tb + ra) * M_DIM + sl * 8;
    const unsigned short* apb = a_buf + (size_t)(e * N_TOK + tb + rb) * M_DIM + sl * 8;

    f32x4 acc[2][2] = {};

    for (int kk = 0; kk < M_DIM / 64; ++kk) {
      *(uint4*)&As[dxa] = *(const uint4*)(apa + kk * 64);
      *(uint4*)&As[dxb] = *(const uint4*)(apb + kk * 64);
      float4 f0 = *(const float4*)(wda + kk * 64);
      float4 f1 = *(const float4*)(wda + kk * 64 + 4);
      *(uint4*)&Ws[dxa] = cvt8(f0, f1);
      f0 = *(const float4*)(wdb + kk * 64);
      f1 = *(const float4*)(wdb + kk * 64 + 4);
      *(uint4*)&Ws[dxb] = cvt8(f0, f1);
      __syncthreads();
#pragma unroll
      for (int ks = 0; ks < 2; ++ks) {
        const int sA = ks * 4 + (lane >> 4);
        bf16x8 a[2], b[2];
#pragma unroll
        for (int f = 0; f < 2; ++f) {
          const int r16 = wm * 32 + f * 16 + (lane & 15);
          a[f] = *(const bf16x8*)&As[r16 * 64 + ((sA ^ (r16 & 7)) << 3)];
          const int c16 = wn * 32 + f * 16 + (lane & 15);
          b[f] = *(const bf16x8*)&Ws[c16 * 64 + ((sA ^ (c16 & 7)) << 3)];
        }
#pragma unroll
        for (int fm = 0; fm < 2; ++fm)
#pragma unroll
          for (int fn = 0; fn < 2; ++fn)
            acc[fm][fn] = __builtin_amdgcn_mfma_f32_16x16x32_bf16(a[fm], b[fn], acc[fm][fn], 0, 0, 0);
      }
      __syncthreads();
    }
#pragma unroll
    for (int fm = 0; fm < 2; ++fm)
#pragma unroll
      for (int fn = 0; fn < 2; ++fn)
#pragma unroll
        for (int rg = 0; rg < 4; ++rg) {
          const int r = tb + wm * 32 + fm * 16 + ((lane >> 4) << 2) + rg;
          if (r < cntE) {
            const int n = (e == 8) ? r : tok_list[e * N_TOK + r];
            const float wgt = (e == 8) ? 1.f : wgt_list[e * N_TOK + r];
            const int h = h0 + wn * 32 + fn * 16 + (lane & 15);
            atomicAdd(y + (size_t)n * H_DIM + h, acc[fm][fn][rg] * wgt);
          }
        }
  }
}

// ---------------- K4: aux loss ----------------
__global__ void k_aux(const int* __restrict__ cnt, const float* __restrict__ pi_sum,
                      float* __restrict__ y_aux) {
  int lane = threadIdx.x;
  float v = 0.f;
  if (lane < 8)
    v = ((float)cnt[lane] * (1.0f / 256.0f)) * (pi_sum[lane] * (1.0f / 1024.0f));
  v += __shfl_xor(v, 32, 64);
  v += __shfl_xor(v, 16, 64);
  v += __shfl_xor(v, 8, 64);
  v += __shfl_xor(v, 4, 64);
  v += __shfl_xor(v, 2, 64);
  v += __shfl_xor(v, 1, 64);
  if (lane == 0) *y_aux = 0.001f * v;
}

extern "C" void kernel_launch(void* const* d_in, const int* in_sizes, int n_in,
                              void* d_out, int out_size, void* d_ws, size_t ws_size,
                              hipStream_t stream) {
  const float* x = (const float*)d_in[0];
  const float* gw = (const float*)d_in[1];
  const float* w_gate = (const float*)d_in[2];
  const float* w_up = (const float*)d_in[3];
  const float* w_down = (const float*)d_in[4];
  const float* sh_gate = (const float*)d_in[5];
  const float* sh_up = (const float*)d_in[6];
  const float* sh_down = (const float*)d_in[7];
  float* y = (float*)d_out;

  char* ws = (char*)d_ws;
  unsigned short* xb = (unsigned short*)ws;                               // 4 MB
  unsigned short* a_buf = (unsigned short*)(ws + (size_t)4 * 1024 * 1024); // 25.9 MB
  char* p = ws + (size_t)4 * 1024 * 1024 + (size_t)9 * N_TOK * M_DIM * 2;
  int* cnt = (int*)p;
  float* pi_sum = (float*)(p + 64);
  int* tok_list = (int*)(p + 128);
  float* wgt_list = (float*)(p + 128 + (size_t)N_EXP * N_TOK * 4);

  k_zero<<<2048, 256, 0, stream>>>(y, (N_TOK * H_DIM) / 4, cnt, pi_sum);
  k_gate<<<N_TOK / 4, 256, 0, stream>>>(x, gw, xb, cnt, pi_sum, tok_list, wgt_list);
  k_gemm1<<<dim3(M_DIM / 64, 9, 4), 256, 0, stream>>>(w_gate, w_up, sh_gate, sh_up,
                                                      xb, cnt, tok_list, a_buf);
  k_gemm2<<<dim3(H_DIM / 64, 9, 4), 256, 0, stream>>>(w_down, sh_down, a_buf, cnt,
                                                      tok_list, wgt_list, y);
  k_aux<<<1, 64, 0, stream>>>(cnt, pi_sum, y + (size_t)N_TOK * H_DIM);
}

// Round 7
// 523.537 us; speedup vs baseline: 1.3861x; 1.3861x over previous
//
#include <hip/hip_runtime.h>
#include <hip/hip_bf16.h>

#define H_DIM 2048
#define M_DIM 1408
#define N_TOK 1024
#define N_EXP 8   // routed experts; expert index 8 = shared expert

typedef __attribute__((ext_vector_type(8))) short bf16x8;
typedef __attribute__((ext_vector_type(4))) float f32x4;

__device__ __forceinline__ unsigned short f2bf(float f) {
  __hip_bfloat16 h = __float2bfloat16(f);
  return __builtin_bit_cast(unsigned short, h);
}

__device__ __forceinline__ uint4 cvt8(const float4 f0, const float4 f1) {
  uint4 o;
  o.x = (unsigned)f2bf(f0.x) | ((unsigned)f2bf(f0.y) << 16);
  o.y = (unsigned)f2bf(f0.z) | ((unsigned)f2bf(f0.w) << 16);
  o.z = (unsigned)f2bf(f1.x) | ((unsigned)f2bf(f1.y) << 16);
  o.w = (unsigned)f2bf(f1.z) | ((unsigned)f2bf(f1.w) << 16);
  return o;
}

// async 16B global->LDS (linear dest: base + lane*16; per-lane global src)
__device__ __forceinline__ void gld16(void* lds, const void* gp) {
  __builtin_amdgcn_global_load_lds(
      (const __attribute__((address_space(1))) unsigned int*)gp,
      (__attribute__((address_space(3))) unsigned int*)lds, 16, 0, 0);
}

// ---------------- K0: zero y + counters ----------------
__global__ void k_zero(float* __restrict__ y, int n4, int* __restrict__ cnt,
                       float* __restrict__ pi_sum) {
  int i = blockIdx.x * blockDim.x + threadIdx.x;
  if (i < n4) {
    float4 z = {0.f, 0.f, 0.f, 0.f};
    *(float4*)(y + (size_t)i * 4) = z;
  }
  if (blockIdx.x == 0 && threadIdx.x < 8) {
    cnt[threadIdx.x] = 0;
    pi_sum[threadIdx.x] = 0.f;
  }
}

// ---------------- K1: gate (fp32) + routing lists + x->bf16 ----------------
__global__ __launch_bounds__(256) void k_gate(
    const float* __restrict__ x, const float* __restrict__ gw,
    unsigned short* __restrict__ xb, int* __restrict__ cnt,
    float* __restrict__ pi_sum, int* __restrict__ tok_list,
    float* __restrict__ wgt_list) {
  const int lane = threadIdx.x & 63;
  const int wv = threadIdx.x >> 6;
  const int n = blockIdx.x * 4 + wv;
  const float* xr = x + (size_t)n * H_DIM;

  __shared__ float ps[8];
  if (threadIdx.x < 8) ps[threadIdx.x] = 0.f;
  __syncthreads();

  float acc[8] = {0.f, 0.f, 0.f, 0.f, 0.f, 0.f, 0.f, 0.f};
  for (int i = 0; i < H_DIM / 64; ++i) {
    float xv = xr[i * 64 + lane];
#pragma unroll
    for (int e = 0; e < 8; ++e) acc[e] += xv * gw[e * H_DIM + i * 64 + lane];
  }
#pragma unroll
  for (int e = 0; e < 8; ++e) {
    acc[e] += __shfl_xor(acc[e], 32, 64);
    acc[e] += __shfl_xor(acc[e], 16, 64);
    acc[e] += __shfl_xor(acc[e], 8, 64);
    acc[e] += __shfl_xor(acc[e], 4, 64);
    acc[e] += __shfl_xor(acc[e], 2, 64);
    acc[e] += __shfl_xor(acc[e], 1, 64);
  }

  // x -> bf16 (coalesced float4 loads, ushort4 stores)
  for (int j = 0; j < H_DIM / 256; ++j) {
    int idx = (j * 64 + lane) * 4;
    float4 v = *(const float4*)(xr + idx);
    ushort4 o;
    o.x = f2bf(v.x); o.y = f2bf(v.y); o.z = f2bf(v.z); o.w = f2bf(v.w);
    *(ushort4*)(xb + (size_t)n * H_DIM + idx) = o;
  }

  if (lane == 0) {
    float mx = acc[0];
#pragma unroll
    for (int e = 1; e < 8; ++e) mx = fmaxf(mx, acc[e]);
    float s[8], ssum = 0.f;
#pragma unroll
    for (int e = 0; e < 8; ++e) { s[e] = expf(acc[e] - mx); ssum += s[e]; }
    float inv = 1.f / ssum;
#pragma unroll
    for (int e = 0; e < 8; ++e) s[e] *= inv;  // softmax scores

    // top-2, earliest index wins ties (matches jax.lax.top_k)
    int i0 = 0;
#pragma unroll
    for (int e = 1; e < 8; ++e) if (s[e] > s[i0]) i0 = e;
    int i1 = (i0 == 0) ? 1 : 0;
#pragma unroll
    for (int e = 0; e < 8; ++e) if (e != i0 && s[e] > s[i1]) i1 = e;

    float w0 = s[i0], w1 = s[i1];
    float rs = 1.f / (w0 + w1 + 1e-20f);

#pragma unroll
    for (int e = 0; e < 8; ++e) atomicAdd(&ps[e], s[e]);

    int p0 = atomicAdd(&cnt[i0], 1);
    tok_list[i0 * N_TOK + p0] = n;
    wgt_list[i0 * N_TOK + p0] = w0 * rs;
    int p1 = atomicAdd(&cnt[i1], 1);
    tok_list[i1 * N_TOK + p1] = n;
    wgt_list[i1 * N_TOK + p1] = w1 * rs;
  }
  __syncthreads();
  if (threadIdx.x < 8) atomicAdd(&pi_sum[threadIdx.x], ps[threadIdx.x]);
}

// ---------------- K2: gathered SwiGLU (gate&up fused), weight-once ----------------
// grid (22*4, 9); block 512. bx: z = bx&3 (token chunk), mt = bx>>2 (m-tile).
__global__ __launch_bounds__(512) void k_gemm1(
    const float* __restrict__ w_gate, const float* __restrict__ w_up,
    const float* __restrict__ sh_gate, const float* __restrict__ sh_up,
    const unsigned short* __restrict__ xb, const int* __restrict__ cnt,
    const int* __restrict__ tok_list, unsigned short* __restrict__ a_buf) {
  const int e = blockIdx.y;
  const int z = blockIdx.x & 3;
  const int m0 = (blockIdx.x >> 2) * 64;
  const int cntE = (e == 8) ? N_TOK : cnt[e];
  const int cb = z * 256;
  if (cb >= cntE) return;
  const float* wg = (e == 8) ? sh_gate : w_gate + (size_t)e * (M_DIM * H_DIM);
  const float* wu = (e == 8) ? sh_up : w_up + (size_t)e * (M_DIM * H_DIM);

  __shared__ unsigned short Xs[256 * 64];  // 32 KB
  __shared__ unsigned short Gs[64 * 64];   // 8 KB
  __shared__ unsigned short Us[64 * 64];   // 8 KB

  const int t = threadIdx.x;
  const int lane = t & 63;
  const int w = t >> 6;          // wave 0..7
  const int wm = w & 1;          // m half (0..1) -> m off wm*32
  const int wt = w >> 1;         // token group (0..3) -> tok off wt*64

  // --- X staging sources: wave w covers rows p*64 + w*8 + (lane>>3), p=0..3 ---
  const int swz_c = ((lane & 7) ^ (lane >> 3)) << 3;  // pre-swizzled col chunk (elems)
  const unsigned short* xsrc[4];
#pragma unroll
  for (int p = 0; p < 4; ++p) {
    int r = p * 64 + (w << 3) + (lane >> 3);  // row in 256-chunk; r&7 == lane>>3
    int rg = cb + r;
    int idx = rg < cntE ? rg : cntE - 1;
    int tok = (e == 8) ? rg : tok_list[e * N_TOK + idx];
    xsrc[p] = xb + (size_t)tok * H_DIM + swz_c;
  }

  // --- W staging: thread t -> row t>>3 (0..63), col chunk t&7 ---
  const int wr = t >> 3, wc = t & 7;
  const float* wgp = wg + (size_t)(m0 + wr) * H_DIM + wc * 8;
  const float* wup = wu + (size_t)(m0 + wr) * H_DIM + wc * 8;
  const int wdst = wr * 64 + (((wc ^ (wr & 7))) << 3);

  f32x4 ag[4][2] = {};
  f32x4 au[4][2] = {};

  for (int kk = 0; kk < H_DIM / 64; ++kk) {
    // async X tile (32 KB) -> LDS, linear dest, pre-swizzled source
#pragma unroll
    for (int p = 0; p < 4; ++p)
      gld16(&Xs[(p * 64 + (w << 3)) * 64], xsrc[p] + kk * 64);
    // weights fp32 -> bf16 -> LDS
    {
      float4 g0 = *(const float4*)(wgp + kk * 64);
      float4 g1 = *(const float4*)(wgp + kk * 64 + 4);
      float4 u0 = *(const float4*)(wup + kk * 64);
      float4 u1 = *(const float4*)(wup + kk * 64 + 4);
      *(uint4*)&Gs[wdst] = cvt8(g0, g1);
      *(uint4*)&Us[wdst] = cvt8(u0, u1);
    }
    __syncthreads();
#pragma unroll
    for (int ks = 0; ks < 2; ++ks) {
      const int sA = ks * 4 + (lane >> 4);
      bf16x8 a[4], bg[2], bu[2];
#pragma unroll
      for (int f = 0; f < 4; ++f) {
        const int r16 = wt * 64 + f * 16 + (lane & 15);
        a[f] = *(const bf16x8*)&Xs[r16 * 64 + ((sA ^ (r16 & 7)) << 3)];
      }
#pragma unroll
      for (int g = 0; g < 2; ++g) {
        const int c16 = wm * 32 + g * 16 + (lane & 15);
        const int off = c16 * 64 + ((sA ^ (c16 & 7)) << 3);
        bg[g] = *(const bf16x8*)&Gs[off];
        bu[g] = *(const bf16x8*)&Us[off];
      }
#pragma unroll
      for (int f = 0; f < 4; ++f)
#pragma unroll
        for (int g = 0; g < 2; ++g) {
          ag[f][g] = __builtin_amdgcn_mfma_f32_16x16x32_bf16(a[f], bg[g], ag[f][g], 0, 0, 0);
          au[f][g] = __builtin_amdgcn_mfma_f32_16x16x32_bf16(a[f], bu[g], au[f][g], 0, 0, 0);
        }
    }
    __syncthreads();
  }

  // epilogue: silu(g)*u -> bf16 a_buf
#pragma unroll
  for (int f = 0; f < 4; ++f)
#pragma unroll
    for (int g = 0; g < 2; ++g)
#pragma unroll
      for (int rg = 0; rg < 4; ++rg) {
        const int row = cb + wt * 64 + f * 16 + ((lane >> 4) << 2) + rg;
        const int col = m0 + wm * 32 + g * 16 + (lane & 15);
        float gv = ag[f][g][rg];
        float uv = au[f][g][rg];
        float av = (gv / (1.f + __expf(-gv))) * uv;
        a_buf[(size_t)(e * N_TOK + row) * M_DIM + col] = f2bf(av);
      }
}

// ---------------- K3: down-proj + weighted scatter, weight-once ----------------
// grid (32*4, 9); block 512.
__global__ __launch_bounds__(512) void k_gemm2(
    const float* __restrict__ w_down, const float* __restrict__ sh_down,
    const unsigned short* __restrict__ a_buf, const int* __restrict__ cnt,
    const int* __restrict__ tok_list, const float* __restrict__ wgt_list,
    float* __restrict__ y) {
  const int e = blockIdx.y;
  const int z = blockIdx.x & 3;
  const int h0 = (blockIdx.x >> 2) * 64;
  const int cntE = (e == 8) ? N_TOK : cnt[e];
  const int cb = z * 256;
  if (cb >= cntE) return;
  const float* wd = (e == 8) ? sh_down : w_down + (size_t)e * (H_DIM * M_DIM);

  __shared__ unsigned short As[256 * 64];  // 32 KB
  __shared__ unsigned short Ws[64 * 64];   // 8 KB

  const int t = threadIdx.x;
  const int lane = t & 63;
  const int w = t >> 6;
  const int wm = w & 1;   // h half
  const int wt = w >> 1;  // token group

  const int swz_c = ((lane & 7) ^ (lane >> 3)) << 3;
  const unsigned short* asrc[4];
#pragma unroll
  for (int p = 0; p < 4; ++p) {
    int r = p * 64 + (w << 3) + (lane >> 3);
    asrc[p] = a_buf + (size_t)(e * N_TOK + cb + r) * M_DIM + swz_c;
  }

  const int wr = t >> 3, wc = t & 7;
  const float* wdp = wd + (size_t)(h0 + wr) * M_DIM + wc * 8;
  const int wdst = wr * 64 + (((wc ^ (wr & 7))) << 3);

  f32x4 acc[4][2] = {};

  for (int kk = 0; kk < M_DIM / 64; ++kk) {
#pragma unroll
    for (int p = 0; p < 4; ++p)
      gld16(&As[(p * 64 + (w << 3)) * 64], asrc[p] + kk * 64);
    {
      float4 f0 = *(const float4*)(wdp + kk * 64);
      float4 f1 = *(const float4*)(wdp + kk * 64 + 4);
      *(uint4*)&Ws[wdst] = cvt8(f0, f1);
    }
    __syncthreads();
#pragma unroll
    for (int ks = 0; ks < 2; ++ks) {
      const int sA = ks * 4 + (lane >> 4);
      bf16x8 a[4], b[2];
#pragma unroll
      for (int f = 0; f < 4; ++f) {
        const int r16 = wt * 64 + f * 16 + (lane & 15);
        a[f] = *(const bf16x8*)&As[r16 * 64 + ((sA ^ (r16 & 7)) << 3)];
      }
#pragma unroll
      for (int g = 0; g < 2; ++g) {
        const int c16 = wm * 32 + g * 16 + (lane & 15);
        b[g] = *(const bf16x8*)&Ws[c16 * 64 + ((sA ^ (c16 & 7)) << 3)];
      }
#pragma unroll
      for (int f = 0; f < 4; ++f)
#pragma unroll
        for (int g = 0; g < 2; ++g)
          acc[f][g] = __builtin_amdgcn_mfma_f32_16x16x32_bf16(a[f], b[g], acc[f][g], 0, 0, 0);
    }
    __syncthreads();
  }

#pragma unroll
  for (int f = 0; f < 4; ++f)
#pragma unroll
    for (int g = 0; g < 2; ++g)
#pragma unroll
      for (int rg = 0; rg < 4; ++rg) {
        const int r = cb + wt * 64 + f * 16 + ((lane >> 4) << 2) + rg;
        if (r < cntE) {
          const int n = (e == 8) ? r : tok_list[e * N_TOK + r];
          const float wgt = (e == 8) ? 1.f : wgt_list[e * N_TOK + r];
          const int h = h0 + wm * 32 + g * 16 + (lane & 15);
          atomicAdd(y + (size_t)n * H_DIM + h, acc[f][g][rg] * wgt);
        }
      }
}

// ---------------- K4: aux loss ----------------
__global__ void k_aux(const int* __restrict__ cnt, const float* __restrict__ pi_sum,
                      float* __restrict__ y_aux) {
  int lane = threadIdx.x;
  float v = 0.f;
  if (lane < 8)
    v = ((float)cnt[lane] * (1.0f / 256.0f)) * (pi_sum[lane] * (1.0f / 1024.0f));
  v += __shfl_xor(v, 32, 64);
  v += __shfl_xor(v, 16, 64);
  v += __shfl_xor(v, 8, 64);
  v += __shfl_xor(v, 4, 64);
  v += __shfl_xor(v, 2, 64);
  v += __shfl_xor(v, 1, 64);
  if (lane == 0) *y_aux = 0.001f * v;
}

extern "C" void kernel_launch(void* const* d_in, const int* in_sizes, int n_in,
                              void* d_out, int out_size, void* d_ws, size_t ws_size,
                              hipStream_t stream) {
  const float* x = (const float*)d_in[0];
  const float* gw = (const float*)d_in[1];
  const float* w_gate = (const float*)d_in[2];
  const float* w_up = (const float*)d_in[3];
  const float* w_down = (const float*)d_in[4];
  const float* sh_gate = (const float*)d_in[5];
  const float* sh_up = (const float*)d_in[6];
  const float* sh_down = (const float*)d_in[7];
  float* y = (float*)d_out;

  char* ws = (char*)d_ws;
  unsigned short* xb = (unsigned short*)ws;                                // 4 MB
  unsigned short* a_buf = (unsigned short*)(ws + (size_t)4 * 1024 * 1024); // 25.9 MB
  char* p = ws + (size_t)4 * 1024 * 1024 + (size_t)9 * N_TOK * M_DIM * 2;
  int* cnt = (int*)p;
  float* pi_sum = (float*)(p + 64);
  int* tok_list = (int*)(p + 128);
  float* wgt_list = (float*)(p + 128 + (size_t)N_EXP * N_TOK * 4);

  k_zero<<<2048, 256, 0, stream>>>(y, (N_TOK * H_DIM) / 4, cnt, pi_sum);
  k_gate<<<N_TOK / 4, 256, 0, stream>>>(x, gw, xb, cnt, pi_sum, tok_list, wgt_list);
  k_gemm1<<<dim3(22 * 4, 9), 512, 0, stream>>>(w_gate, w_up, sh_gate, sh_up,
                                               xb, cnt, tok_list, a_buf);
  k_gemm2<<<dim3(32 * 4, 9), 512, 0, stream>>>(w_down, sh_down, a_buf, cnt,
                                               tok_list, wgt_list, y);
  k_aux<<<1, 64, 0, stream>>>(cnt, pi_sum, y + (size_t)N_TOK * H_DIM);
}